// Round 13
// baseline (1666.726 us; speedup 1.0000x reference)
//
#include <hip/hip_runtime.h>

#define N_NODES  50000
#define R_REL    3
#define E_EDGES  50000
#define EP_EDGES 100000
#define ELL_CAP  32

typedef __attribute__((ext_vector_type(8))) short  short8;
typedef __attribute__((ext_vector_type(8))) unsigned short ushort8;
typedef __attribute__((ext_vector_type(4))) float  floatx4;

static inline int cdiv_h(int a, int b) { return (a + b - 1) / b; }

__device__ inline unsigned short f2b(float f) {
    union { float f; unsigned u; } v; v.f = f;
    return (unsigned short)((v.u + 0x7FFF + ((v.u >> 16) & 1)) >> 16);
}
__device__ inline float b2f(unsigned short h) {
    union { unsigned u; float f; } v; v.u = ((unsigned)h) << 16;
    return v.f;
}

#define GLDS16(gp, lp) __builtin_amdgcn_global_load_lds( \
    (const __attribute__((address_space(1))) void*)(gp), \
    (__attribute__((address_space(3))) void*)(lp), 16, 0, 0)

// ---------------- degree count + ELL fill + out-active row compaction ----------------
__global__ void count_fill_kernel(const int* __restrict__ src, const int* __restrict__ dst,
                                  int* __restrict__ outcnt, int* __restrict__ incnt,
                                  int* __restrict__ ell, int* __restrict__ nrows,
                                  int* __restrict__ rows, int* __restrict__ mapc) {
    int i = blockIdx.x * blockDim.x + threadIdx.x;
    if (i >= R_REL * E_EDGES) return;
    int r = i / E_EDGES;
    int s = src[i], d = dst[i];
    int o = atomicAdd(&outcnt[r * N_NODES + s], 1);
    if (o == 0) {   // first out-edge of (r,s): assign compacted row index
        int idx = atomicAdd(&nrows[r], 1);
        rows[r * N_NODES + idx] = s;
        mapc[r * N_NODES + s]   = idx;
    }
    int k = atomicAdd(&incnt[r * N_NODES + d], 1);
    if (k < ELL_CAP)
        ell[((size_t)(r * N_NODES + d) << 5) + k] = s;
}

__global__ void norm_kernel(const int* __restrict__ cnt, float* __restrict__ nrm, int n) {
    int i = blockIdx.x * blockDim.x + threadIdx.x;
    if (i < n) nrm[i] = rsqrtf(fmaxf((float)cnt[i], 1.0f));
}

// ---------------- x->bf16 + all weight transposes (4 layers + Wp1), one launch ----------
#define F2B_TOT 3200000   // N_NODES*512/8
__global__ void prep_all_kernel(
        const float* __restrict__ x, unsigned short* __restrict__ xb,
        const float* __restrict__ W0, const float* __restrict__ W1,
        const float* __restrict__ W2, const float* __restrict__ W3,
        const float* __restrict__ Wp1,
        unsigned short* __restrict__ Wt0, unsigned short* __restrict__ Wt1,
        unsigned short* __restrict__ Wt2, unsigned short* __restrict__ Wt3,
        unsigned short* __restrict__ But) {
    int i = blockIdx.x * blockDim.x + threadIdx.x;
    if (i < F2B_TOT) {
        float4 a = ((const float4*)x)[2 * i];
        float4 b = ((const float4*)x)[2 * i + 1];
        ushort8 o;
        o[0] = f2b(a.x); o[1] = f2b(a.y); o[2] = f2b(a.z); o[3] = f2b(a.w);
        o[4] = f2b(b.x); o[5] = f2b(b.y); o[6] = f2b(b.z); o[7] = f2b(b.w);
        ((ushort8*)xb)[i] = o;
        return;
    }
    i -= F2B_TOT;
    if (i < 786432) {                       // L0: K=512 dout=512 rows=1536
        int k = i & 511, nall = i >> 9, r = nall >> 9, n = nall & 511;
        Wt0[i] = f2b(W0[(((size_t)r << 9) + k) * 512 + n]);
    } else if (i < 1179648) {               // L1: K=512 dout=256 rows=768
        int j = i - 786432;
        int k = j & 511, nall = j >> 9, r = nall >> 8, n = nall & 255;
        Wt1[j] = f2b(W1[(((size_t)r << 9) + k) * 256 + n]);
    } else if (i < 1277952) {               // L2: K=256 dout=128 rows=384
        int j = i - 1179648;
        int k = j & 255, nall = j >> 8, r = nall >> 7, n = nall & 127;
        Wt2[j] = f2b(W2[(((size_t)r << 8) + k) * 128 + n]);
    } else if (i < 1310720) {               // L3: K=128 dout=64 rows=256 (pad 192..255)
        int j = i - 1277952;
        int k = j & 127, nall = j >> 7, r = nall >> 6, n = nall & 63;
        Wt3[j] = (r < R_REL) ? f2b(W3[(((size_t)r << 7) + k) * 64 + n]) : (unsigned short)0;
    } else if (i < 1318912) {               // Wp1 -> But[128][64]
        int j = i - 1310720;
        int k = j & 63, jo = j >> 6, jj = jo & 63, half = jo >> 6;
        But[j] = f2b(Wp1[(size_t)(half * 64 + k) * 64 + jj]);
    }
}

// ---------------- R10 fused MFMA GEMM (unchanged; used for L2/L3/UV) ----------------
// BM=128 BN=128 BK=64, 4 waves, wave tile 64x64; A+B via global_load_lds,
// 8-chunk XOR swizzle (0 conflicts), 2 barriers / 64-K. K%64==0, NdPad%128==0.
__global__ __launch_bounds__(256) void gemm_bf16_fused(
        const unsigned short* __restrict__ A, const unsigned short* __restrict__ Bt,
        unsigned short* __restrict__ C, const float* __restrict__ sn,
        int M, int K, int NdPad, int dout) {
    __shared__ unsigned short As[8192];   // [128][64]
    __shared__ unsigned short Bs[8192];   // [128][64]

    const int nN = gridDim.x, nM = gridDim.y;
    int p = blockIdx.y * nN + blockIdx.x;
    const int nig = nN << 3;
    int group = p / nig;
    int rem = p - group * nig;
    int gs = nM - (group << 3); if (gs > 8) gs = 8;
    int mb = (group << 3) + rem % gs;
    int nb = rem / gs;
    const int m0 = mb * 128, n0 = nb * 128;

    const int tid  = threadIdx.x;
    const int w    = tid >> 6;
    const int lane = tid & 63;
    const int wm   = w & 1;
    const int wn   = w >> 1;
    const int lrow8 = lane >> 3;
    const int cs    = ((lane & 7) ^ lrow8) << 3;

    floatx4 acc[4][4];
#pragma unroll
    for (int i = 0; i < 4; ++i)
#pragma unroll
        for (int j = 0; j < 4; ++j) acc[i][j] = (floatx4){0.f, 0.f, 0.f, 0.f};

    const int mrow  = lane & 15;
    const int phys0 = ((lane >> 4) ^ (lane & 7)) << 3;
    const int phys1 = phys0 ^ 32;

    for (int k0 = 0; k0 < K; k0 += 64) {
#pragma unroll
        for (int i = 0; i < 4; ++i) {
            int rr = i * 32 + 8 * w + lrow8;
            GLDS16(A  + (size_t)(m0 + rr) * K + k0 + cs, As + (i * 32 + 8 * w) * 64);
        }
#pragma unroll
        for (int i = 0; i < 4; ++i) {
            int rr = i * 32 + 8 * w + lrow8;
            GLDS16(Bt + (size_t)(n0 + rr) * K + k0 + cs, Bs + (i * 32 + 8 * w) * 64);
        }
        __syncthreads();

#pragma unroll
        for (int h = 0; h < 2; ++h) {
            const int ph = h ? phys1 : phys0;
            short8 a[4], b[4];
#pragma unroll
            for (int nt = 0; nt < 4; ++nt)
                b[nt] = *(const short8*)&Bs[(wn * 64 + nt * 16 + mrow) * 64 + ph];
#pragma unroll
            for (int mt = 0; mt < 4; ++mt)
                a[mt] = *(const short8*)&As[(wm * 64 + mt * 16 + mrow) * 64 + ph];
#pragma unroll
            for (int mt = 0; mt < 4; ++mt)
#pragma unroll
                for (int nt = 0; nt < 4; ++nt)
                    acc[mt][nt] = __builtin_amdgcn_mfma_f32_16x16x32_bf16(a[mt], b[nt],
                                                                          acc[mt][nt], 0, 0, 0);
        }
        __syncthreads();
    }

    const int colb = n0 + wn * 64;
    const int r_quad = colb / dout;
    if (sn && r_quad >= R_REL) return;
    const int col = colb + (lane & 15);
    const int rb0 = m0 + wm * 64 + (lane >> 4) * 4;
#pragma unroll
    for (int mt = 0; mt < 4; ++mt) {
#pragma unroll
        for (int reg = 0; reg < 4; ++reg) {
            int row = rb0 + mt * 16 + reg;
            if (row < M) {
                float rs = sn ? sn[(size_t)r_quad * N_NODES + row] : 1.0f;
#pragma unroll
                for (int nt = 0; nt < 4; ++nt)
                    C[(size_t)row * NdPad + col + nt * 16] = f2b(acc[mt][nt][reg] * rs);
            }
        }
    }
}

// ---------------- compacted per-relation GEMM (L0/L1) ----------------
// C[m][n] = (A[rows[m]][:].Bt[n][:]) * sn[rows[m]], m < M_r (runtime, from nrows).
// Same R10 K-loop (BK=64, XOR swizzle, 2 barriers). Nd = dout (512 or 256), %128==0.
__global__ __launch_bounds__(256) void gemm_bf16_compact(
        const unsigned short* __restrict__ A, const unsigned short* __restrict__ Bt,
        unsigned short* __restrict__ C, const float* __restrict__ sn,
        const int* __restrict__ rows, const int* __restrict__ nrows,
        int K, int Nd) {
    __shared__ unsigned short As[8192];
    __shared__ unsigned short Bs[8192];

    const int M_r = *nrows;
    const int nN = gridDim.x, nM = gridDim.y;
    int p = blockIdx.y * nN + blockIdx.x;
    const int nig = nN << 3;
    int group = p / nig;
    int rem = p - group * nig;
    int gs = nM - (group << 3); if (gs > 8) gs = 8;
    int mb = (group << 3) + rem % gs;
    int nb = rem / gs;
    const int m0 = mb * 128, n0 = nb * 128;
    if (m0 >= M_r) return;

    const int tid  = threadIdx.x;
    const int w    = tid >> 6;
    const int lane = tid & 63;
    const int wm   = w & 1;
    const int wn   = w >> 1;
    const int lrow8 = lane >> 3;
    const int cs    = ((lane & 7) ^ lrow8) << 3;

    // hoist per-thread A row pointers (k-invariant)
    const unsigned short* abase[4];
#pragma unroll
    for (int i = 0; i < 4; ++i) {
        int mm = m0 + i * 32 + 8 * w + lrow8;
        if (mm >= M_r) mm = M_r - 1;
        abase[i] = A + (size_t)rows[mm] * K;
    }

    floatx4 acc[4][4];
#pragma unroll
    for (int i = 0; i < 4; ++i)
#pragma unroll
        for (int j = 0; j < 4; ++j) acc[i][j] = (floatx4){0.f, 0.f, 0.f, 0.f};

    const int mrow  = lane & 15;
    const int phys0 = ((lane >> 4) ^ (lane & 7)) << 3;
    const int phys1 = phys0 ^ 32;

    for (int k0 = 0; k0 < K; k0 += 64) {
#pragma unroll
        for (int i = 0; i < 4; ++i)
            GLDS16(abase[i] + k0 + cs, As + (i * 32 + 8 * w) * 64);
#pragma unroll
        for (int i = 0; i < 4; ++i) {
            int rr = i * 32 + 8 * w + lrow8;
            GLDS16(Bt + (size_t)(n0 + rr) * K + k0 + cs, Bs + (i * 32 + 8 * w) * 64);
        }
        __syncthreads();

#pragma unroll
        for (int h = 0; h < 2; ++h) {
            const int ph = h ? phys1 : phys0;
            short8 a[4], b[4];
#pragma unroll
            for (int nt = 0; nt < 4; ++nt)
                b[nt] = *(const short8*)&Bs[(wn * 64 + nt * 16 + mrow) * 64 + ph];
#pragma unroll
            for (int mt = 0; mt < 4; ++mt)
                a[mt] = *(const short8*)&As[(wm * 64 + mt * 16 + mrow) * 64 + ph];
#pragma unroll
            for (int mt = 0; mt < 4; ++mt)
#pragma unroll
                for (int nt = 0; nt < 4; ++nt)
                    acc[mt][nt] = __builtin_amdgcn_mfma_f32_16x16x32_bf16(a[mt], b[nt],
                                                                          acc[mt][nt], 0, 0, 0);
        }
        __syncthreads();
    }

    const int col = n0 + wn * 64 + (lane & 15);
    const int rb0 = m0 + wm * 64 + (lane >> 4) * 4;
#pragma unroll
    for (int mt = 0; mt < 4; ++mt) {
#pragma unroll
        for (int reg = 0; reg < 4; ++reg) {
            int row = rb0 + mt * 16 + reg;
            if (row < M_r) {
                float rs = sn[rows[row]];
#pragma unroll
                for (int nt = 0; nt < 4; ++nt)
                    C[(size_t)row * Nd + col + nt * 16] = f2b(acc[mt][nt][reg] * rs);
            }
        }
    }
}

// ---------------- gather over compacted hr (L0/L1) ----------------
// hr_r = hrc + r*N_NODES*dout (compacted rows, stride dout); src row via mapc.
__global__ void gather3_compact(const unsigned short* __restrict__ hrc,
                                const int* __restrict__ mapc,
                                const int* __restrict__ ell, const int* __restrict__ incnt,
                                const float* __restrict__ dn, const float* __restrict__ bias,
                                unsigned short* __restrict__ outh,
                                int lgc, int total, int do_relu, int dout) {
    int i = blockIdx.x * blockDim.x + threadIdx.x;
    if (i >= total) return;
    int d = i >> lgc;
    int c = i & ((1 << lgc) - 1);
    const int d8 = dout >> 3;
    float acc[8] = {0.f, 0.f, 0.f, 0.f, 0.f, 0.f, 0.f, 0.f};
#pragma unroll
    for (int r = 0; r < R_REL; ++r) {
        int nr = incnt[r * N_NODES + d];
        nr = nr < ELL_CAP ? nr : ELL_CAP;
        size_t base = (size_t)(r * N_NODES + d) << 5;
        const ushort8* hr8 = (const ushort8*)(hrc + (size_t)r * N_NODES * dout);
        float a[8] = {0.f, 0.f, 0.f, 0.f, 0.f, 0.f, 0.f, 0.f};
        for (int k = 0; k < nr; ++k) {
            int s = ell[base + k];
            int rowc = mapc[r * N_NODES + s];
            ushort8 v = hr8[(size_t)rowc * d8 + c];
#pragma unroll
            for (int j = 0; j < 8; ++j) a[j] += b2f(v[j]);
        }
        float dnd = dn[r * N_NODES + d];
#pragma unroll
        for (int j = 0; j < 8; ++j) acc[j] += dnd * a[j];
    }
    int f = c << 3;
#pragma unroll
    for (int j = 0; j < 8; ++j)
        acc[j] += bias[f + j] + bias[dout + f + j] + bias[2 * dout + f + j];
    if (do_relu) {
#pragma unroll
        for (int j = 0; j < 8; ++j) acc[j] = fmaxf(acc[j], 0.f);
    }
    ushort8 o;
#pragma unroll
    for (int j = 0; j < 8; ++j) o[j] = f2b(acc[j]);
    ((ushort8*)outh)[i] = o;
}

// ---------------- fused 3-relation ELL gather, uncompacted hr (L2/L3) ----------------
__global__ void gather3_kernel(const unsigned short* __restrict__ hr, int S8, int d8,
                               const int* __restrict__ ell, const int* __restrict__ incnt,
                               const float* __restrict__ dn, const float* __restrict__ bias,
                               unsigned short* __restrict__ outh,
                               int lgc, int total, int do_relu, int dout) {
    int i = blockIdx.x * blockDim.x + threadIdx.x;
    if (i >= total) return;
    int d = i >> lgc;
    int c = i & ((1 << lgc) - 1);
    float acc[8] = {0.f, 0.f, 0.f, 0.f, 0.f, 0.f, 0.f, 0.f};
    const ushort8* hr8 = (const ushort8*)hr;
#pragma unroll
    for (int r = 0; r < R_REL; ++r) {
        int nr = incnt[r * N_NODES + d];
        nr = nr < ELL_CAP ? nr : ELL_CAP;
        size_t base = (size_t)(r * N_NODES + d) << 5;
        float a[8] = {0.f, 0.f, 0.f, 0.f, 0.f, 0.f, 0.f, 0.f};
        for (int k = 0; k < nr; ++k) {
            int s = ell[base + k];
            ushort8 v = hr8[(size_t)s * S8 + r * d8 + c];
#pragma unroll
            for (int j = 0; j < 8; ++j) a[j] += b2f(v[j]);
        }
        float dnd = dn[r * N_NODES + d];
#pragma unroll
        for (int j = 0; j < 8; ++j) acc[j] += dnd * a[j];
    }
    int f = c << 3;
#pragma unroll
    for (int j = 0; j < 8; ++j)
        acc[j] += bias[f + j] + bias[dout + f + j] + bias[2 * dout + f + j];
    if (do_relu) {
#pragma unroll
        for (int j = 0; j < 8; ++j) acc[j] = fmaxf(acc[j], 0.f);
    }
    ushort8 o;
#pragma unroll
    for (int j = 0; j < 8; ++j) o[j] = f2b(acc[j]);
    ((ushort8*)outh)[i] = o;
}

// ---------------- edge scores from UV: score = Wp2 . relu(U[s]+V[d]+bp1) + bp2 ----------
__global__ __launch_bounds__(256) void edge_score_kernel(
        const unsigned short* __restrict__ UV,
        const int* __restrict__ pos_src, const int* __restrict__ pos_dst,
        const int* __restrict__ neg_src, const int* __restrict__ neg_dst,
        const float* __restrict__ bp1, const float* __restrict__ Wp2,
        const float* __restrict__ bp2, float* __restrict__ outp) {
    __shared__ float sb[64], sw[64];
    int t = threadIdx.x;
    if (t < 64) { sb[t] = bp1[t]; sw[t] = Wp2[t]; }
    __syncthreads();
    int i = blockIdx.x * blockDim.x + t;
    if (i >= 2 * EP_EDGES) return;
    int s, d;
    if (i < EP_EDGES) { s = pos_src[i]; d = pos_dst[i]; }
    else              { s = neg_src[i - EP_EDGES]; d = neg_dst[i - EP_EDGES]; }
    const ushort8* UV8 = (const ushort8*)UV;
    float acc = bp2[0];
#pragma unroll
    for (int jv = 0; jv < 8; ++jv) {
        ushort8 u = UV8[(size_t)s * 16 + jv];
        ushort8 v = UV8[(size_t)d * 16 + 8 + jv];
#pragma unroll
        for (int j = 0; j < 8; ++j) {
            float z = b2f(u[j]) + b2f(v[j]) + sb[jv * 8 + j];
            acc = fmaf(fmaxf(z, 0.f), sw[jv * 8 + j], acc);
        }
    }
    outp[i] = acc;
}

extern "C" void kernel_launch(void* const* d_in, const int* in_sizes, int n_in,
                              void* d_out, int out_size, void* d_ws, size_t ws_size,
                              hipStream_t stream) {
    const float* x       = (const float*)d_in[0];
    const int*   rel_src = (const int*)d_in[1];
    const int*   rel_dst = (const int*)d_in[2];
    const int*   pos_src = (const int*)d_in[3];
    const int*   pos_dst = (const int*)d_in[4];
    const int*   neg_src = (const int*)d_in[5];
    const int*   neg_dst = (const int*)d_in[6];
    const float* W[4]    = {(const float*)d_in[7],  (const float*)d_in[9],
                            (const float*)d_in[11], (const float*)d_in[13]};
    const float* bias[4] = {(const float*)d_in[8],  (const float*)d_in[10],
                            (const float*)d_in[12], (const float*)d_in[14]};
    const float* Wp1 = (const float*)d_in[15];
    const float* bp1 = (const float*)d_in[16];
    const float* Wp2 = (const float*)d_in[17];
    const float* bp2 = (const float*)d_in[18];
    float* out = (float*)d_out;

    // workspace layout
    size_t NP = (size_t)(N_NODES + 128);
    unsigned short* xb  = (unsigned short*)d_ws;          // NP x 512 (reused for UV later)
    unsigned short* h0  = xb + NP * 512;                  // NP x 512
    unsigned short* h1  = h0 + NP * 512;                  // NP x 256
    unsigned short* hr  = h1 + NP * 256;                  // 3 x N x 512 max
    unsigned short* Wt0 = hr + (size_t)R_REL * N_NODES * 512;
    unsigned short* Wt1 = Wt0 + 786432;
    unsigned short* Wt2 = Wt1 + 393216;
    unsigned short* Wt3 = Wt2 + 98304;
    unsigned short* But = Wt3 + 32768;                    // 128*64
    float* sn   = (float*)(But + 128 * 64);
    float* dn   = sn + (size_t)R_REL * N_NODES;
    int* outcnt = (int*)(dn + (size_t)R_REL * N_NODES);
    int* incnt  = outcnt + (size_t)R_REL * N_NODES;
    int* nrows  = incnt + (size_t)R_REL * N_NODES;        // 3 counters (+pad to 16)
    int* rows   = nrows + 16;                             // [R][N] compact->node
    int* mapc   = rows + (size_t)R_REL * N_NODES;         // [R][N] node->compact
    int* ell    = mapc + (size_t)R_REL * N_NODES;         // 3*N*32 ints
    unsigned short* UV = xb;                              // N x 128 (after layers done)

    hipMemsetAsync(outcnt, 0, sizeof(int) * (2 * R_REL * N_NODES + 16), stream);
    count_fill_kernel<<<cdiv_h(R_REL * E_EDGES, 256), 256, 0, stream>>>(
        rel_src, rel_dst, outcnt, incnt, ell, nrows, rows, mapc);
    norm_kernel<<<cdiv_h(2 * R_REL * N_NODES, 256), 256, 0, stream>>>(
        outcnt, sn, 2 * R_REL * N_NODES);

    prep_all_kernel<<<cdiv_h(F2B_TOT + 1318912, 256), 256, 0, stream>>>(
        x, xb, W[0], W[1], W[2], W[3], Wp1, Wt0, Wt1, Wt2, Wt3, But);

    const int nMfull = cdiv_h(N_NODES, 128);   // 391

    // ---- L0 (compacted): per relation, A=xb rows[r], Bt seg, C=hr + r*N*512 ----
    for (int r = 0; r < R_REL; ++r) {
        gemm_bf16_compact<<<dim3(4, nMfull), 256, 0, stream>>>(
            xb, Wt0 + (size_t)r * 512 * 512, hr + (size_t)r * N_NODES * 512,
            sn + (size_t)r * N_NODES, rows + (size_t)r * N_NODES, nrows + r, 512, 512);
    }
    gather3_compact<<<cdiv_h(N_NODES << 6, 256), 256, 0, stream>>>(
        hr, mapc, ell, incnt, dn, bias[0], h0, 6, N_NODES << 6, 1, 512);

    // ---- L1 (compacted): A=h0, dout=256 ----
    for (int r = 0; r < R_REL; ++r) {
        gemm_bf16_compact<<<dim3(2, nMfull), 256, 0, stream>>>(
            h0, Wt1 + (size_t)r * 256 * 512, hr + (size_t)r * N_NODES * 256,
            sn + (size_t)r * N_NODES, rows + (size_t)r * N_NODES, nrows + r, 512, 256);
    }
    gather3_compact<<<cdiv_h(N_NODES << 5, 256), 256, 0, stream>>>(
        hr, mapc, ell, incnt, dn, bias[1], h1, 5, N_NODES << 5, 1, 256);

    // ---- L2 (fused): K=256, NdPad=384, dout=128 ----
    gemm_bf16_fused<<<dim3(3, nMfull), 256, 0, stream>>>(h1, Wt2, hr, sn,
                                                         N_NODES, 256, 384, 128);
    gather3_kernel<<<cdiv_h(N_NODES << 4, 256), 256, 0, stream>>>(
        hr, 48, 16, ell, incnt, dn, bias[2], h0, 4, N_NODES << 4, 1, 128);

    // ---- L3 (fused): K=128, NdPad=256, dout=64, no ReLU ----
    gemm_bf16_fused<<<dim3(2, nMfull), 256, 0, stream>>>(h0, Wt3, hr, sn,
                                                         N_NODES, 128, 256, 64);
    gather3_kernel<<<cdiv_h(N_NODES << 3, 256), 256, 0, stream>>>(
        hr, 32, 8, ell, incnt, dn, bias[3], h1, 3, N_NODES << 3, 0, 64);

    // ---- UV = h_final @ [Wp1_top | Wp1_bot]  (M=N, K=64, Nd=128) ----
    gemm_bf16_fused<<<dim3(1, nMfull), 256, 0, stream>>>(h1, But, UV, nullptr,
                                                         N_NODES, 64, 128, 128);

    edge_score_kernel<<<cdiv_h(2 * EP_EDGES, 256), 256, 0, stream>>>(
        UV, pos_src, pos_dst, neg_src, neg_dst, bp1, Wp2, bp2, out);
}